// Round 1
// baseline (304.900 us; speedup 1.0000x reference)
//
#include <hip/hip_runtime.h>
#include <hip/hip_bf16.h>

typedef short short8 __attribute__((ext_vector_type(8)));
typedef short bf16x8 __attribute__((ext_vector_type(8)));
typedef float f32x4 __attribute__((ext_vector_type(4)));
typedef float f4 __attribute__((ext_vector_type(4)));

constexpr int Bn = 16;     // batch
constexpr int C  = 256;    // channels
constexpr int NT = 1024;   // tokens (h*w)
constexpr int NH = 8;      // heads
constexpr int DH = 64;     // dim head
constexpr int INNER = 512;
constexpr int QKVD = 1536;

#define DEVFN __device__ __forceinline__

DEVFN float b2f(unsigned short u) {
    unsigned int x = ((unsigned int)u) << 16;
    float f;
    __builtin_memcpy(&f, &x, 4);
    return f;
}
DEVFN unsigned short f2b(float f) {
    unsigned int x;
    __builtin_memcpy(&x, &f, 4);
    unsigned int r = (x + 0x7fffu + ((x >> 16) & 1u)) >> 16;
    return (unsigned short)r;
}

// ---------------- Kernel A: QKV projection ----------------
// out qkv[b][t][j] (bf16), j in [0,1536): head*192 + {q:0-63, k:64-127, v:128-191}
__global__ __launch_bounds__(256) void qkv_gemm(const float* __restrict__ x,
                                                const float* __restrict__ Wqkv,
                                                const float* __restrict__ bqkv,
                                                short* __restrict__ qkv) {
    __shared__ __align__(16) short As[128][40];   // [t][c]
    __shared__ __align__(16) short Bs[128][40];   // [j][c] (transposed)

    const int tid  = threadIdx.x;
    const int lane = tid & 63;
    const int w    = tid >> 6;
    const int wr   = w >> 1, wc = w & 1;
    const int j0   = blockIdx.x * 128;
    const int t0   = blockIdx.y * 128;
    const int b    = blockIdx.z;
    const int l15  = lane & 15;
    const int g    = lane >> 4;

    f32x4 acc[4][4] = {};

    const float* xb = x + (size_t)b * C * NT;

    for (int c0 = 0; c0 < C; c0 += 32) {
        // A tile: As[t][c] = x[b][c0+c][t0+t]  (coalesced float4 along t)
        #pragma unroll
        for (int i = 0; i < 4; ++i) {
            int idx = tid + i * 256;            // 0..1023
            int t4 = (idx & 31) * 4, c = idx >> 5;
            f4 v = *(const f4*)&xb[(size_t)(c0 + c) * NT + t0 + t4];
            #pragma unroll
            for (int j = 0; j < 4; ++j) As[t4 + j][c] = (short)f2b(v[j]);
        }
        // B tile transposed: Bs[j][c] = Wqkv[c0+c][j0+j] (coalesced float4 along j)
        #pragma unroll
        for (int i = 0; i < 4; ++i) {
            int idx = tid + i * 256;
            int j4 = (idx & 31) * 4, c = idx >> 5;
            f4 v = *(const f4*)&Wqkv[(size_t)(c0 + c) * QKVD + j0 + j4];
            #pragma unroll
            for (int j = 0; j < 4; ++j) Bs[j4 + j][c] = (short)f2b(v[j]);
        }
        __syncthreads();

        bf16x8 a[4], bfr[4];
        #pragma unroll
        for (int m = 0; m < 4; ++m)
            a[m] = *(const bf16x8*)&As[wr * 64 + m * 16 + l15][g * 8];
        #pragma unroll
        for (int n = 0; n < 4; ++n)
            bfr[n] = *(const bf16x8*)&Bs[wc * 64 + n * 16 + l15][g * 8];
        #pragma unroll
        for (int m = 0; m < 4; ++m)
            #pragma unroll
            for (int n = 0; n < 4; ++n)
                acc[m][n] = __builtin_amdgcn_mfma_f32_16x16x32_bf16(a[m], bfr[n], acc[m][n], 0, 0, 0);
        __syncthreads();
    }

    short* qb = qkv + (size_t)b * NT * QKVD;
    #pragma unroll
    for (int m = 0; m < 4; ++m) {
        int t = t0 + wr * 64 + m * 16 + g * 4;
        #pragma unroll
        for (int n = 0; n < 4; ++n) {
            int j = j0 + wc * 64 + n * 16 + l15;
            float bias = bqkv[j];
            #pragma unroll
            for (int r = 0; r < 4; ++r)
                qb[(size_t)(t + r) * QKVD + j] = (short)f2b(acc[m][n][r] + bias);
        }
    }
}

// ---------------- Kernel B: flash attention ----------------
// res[b][t][h*64+d] (bf16)
__global__ __launch_bounds__(256) void attn(const short* __restrict__ qkv,
                                            short* __restrict__ res) {
    __shared__ __align__(16) short Q_lds[64][72];
    __shared__ __align__(16) short K_lds[64][72];
    __shared__ __align__(16) short Vt_lds[64][72];  // [d][key]
    __shared__ __align__(16) short P_lds[64][72];   // [q][key]

    const int tid  = threadIdx.x;
    const int lane = tid & 63;
    const int w    = tid >> 6;
    const int l15  = lane & 15;
    const int g    = lane >> 4;

    const int q0 = blockIdx.x * 64;
    const int h  = blockIdx.y;
    const int b  = blockIdx.z;

    const short* qkvb = qkv + (size_t)b * NT * QKVD + (size_t)h * 3 * DH;

    // Q tile, scaled by 1/8 (exact in bf16)
    for (int i = tid; i < 512; i += 256) {
        int row = i >> 3, dc = i & 7;
        short8 qv = *(const short8*)(qkvb + (size_t)(q0 + row) * QKVD + dc * 8);
        short8 qs;
        #pragma unroll
        for (int j = 0; j < 8; ++j)
            qs[j] = (short)f2b(b2f((unsigned short)qv[j]) * 0.125f);
        *(short8*)&Q_lds[row][dc * 8] = qs;
    }

    float m_run[4], l_run[4];
    f32x4 o_acc[4] = {};
    #pragma unroll
    for (int r = 0; r < 4; ++r) { m_run[r] = -1e30f; l_run[r] = 0.f; }

    for (int kt = 0; kt < NT / 64; ++kt) {
        const int k0 = kt * 64;
        for (int i = tid; i < 512; i += 256) {
            int row = i >> 3, dc = i & 7;
            *(short8*)&K_lds[row][dc * 8] =
                *(const short8*)(qkvb + (size_t)(k0 + row) * QKVD + DH + dc * 8);
        }
        for (int i = tid; i < 512; i += 256) {
            int row = i >> 3, dc = i & 7;
            short8 vv = *(const short8*)(qkvb + (size_t)(k0 + row) * QKVD + 2 * DH + dc * 8);
            #pragma unroll
            for (int j = 0; j < 8; ++j)
                Vt_lds[dc * 8 + j][row] = vv[j];
        }
        __syncthreads();

        // S = Q·K^T for this wave's 16 q-rows × 64 keys
        bf16x8 aq0 = *(const bf16x8*)&Q_lds[w * 16 + l15][g * 8];
        bf16x8 aq1 = *(const bf16x8*)&Q_lds[w * 16 + l15][32 + g * 8];
        f32x4 s[4];
        #pragma unroll
        for (int n = 0; n < 4; ++n) {
            bf16x8 bk0 = *(const bf16x8*)&K_lds[n * 16 + l15][g * 8];
            bf16x8 bk1 = *(const bf16x8*)&K_lds[n * 16 + l15][32 + g * 8];
            f32x4 z = {};
            z = __builtin_amdgcn_mfma_f32_16x16x32_bf16(aq0, bk0, z, 0, 0, 0);
            s[n] = __builtin_amdgcn_mfma_f32_16x16x32_bf16(aq1, bk1, z, 0, 0, 0);
        }

        // online softmax (rows live across 16-lane groups; reduce over lanes 0-15 of group)
        float mt[4];
        #pragma unroll
        for (int r = 0; r < 4; ++r) {
            float v = fmaxf(fmaxf(s[0][r], s[1][r]), fmaxf(s[2][r], s[3][r]));
            #pragma unroll
            for (int msk = 1; msk < 16; msk <<= 1)
                v = fmaxf(v, __shfl_xor(v, msk, 64));
            mt[r] = v;
        }
        float alpha[4], mnew[4];
        #pragma unroll
        for (int r = 0; r < 4; ++r) {
            mnew[r] = fmaxf(m_run[r], mt[r]);
            alpha[r] = __expf(m_run[r] - mnew[r]);
            m_run[r] = mnew[r];
        }
        float p[4][4], rs[4];
        #pragma unroll
        for (int r = 0; r < 4; ++r) rs[r] = 0.f;
        #pragma unroll
        for (int n = 0; n < 4; ++n)
            #pragma unroll
            for (int r = 0; r < 4; ++r) {
                p[n][r] = __expf(s[n][r] - mnew[r]);
                rs[r] += p[n][r];
            }
        #pragma unroll
        for (int r = 0; r < 4; ++r) {
            float v = rs[r];
            #pragma unroll
            for (int msk = 1; msk < 16; msk <<= 1)
                v += __shfl_xor(v, msk, 64);
            l_run[r] = l_run[r] * alpha[r] + v;
        }
        #pragma unroll
        for (int df = 0; df < 4; ++df)
            #pragma unroll
            for (int r = 0; r < 4; ++r)
                o_acc[df][r] *= alpha[r];

        // P -> LDS (bf16), wave-private 16-row slice, no barrier needed
        #pragma unroll
        for (int n = 0; n < 4; ++n)
            #pragma unroll
            for (int r = 0; r < 4; ++r)
                P_lds[w * 16 + g * 4 + r][n * 16 + l15] = (short)f2b(p[n][r]);

        // O += P·V
        #pragma unroll
        for (int sstep = 0; sstep < 2; ++sstep) {
            bf16x8 ap = *(const bf16x8*)&P_lds[w * 16 + l15][sstep * 32 + g * 8];
            #pragma unroll
            for (int df = 0; df < 4; ++df) {
                bf16x8 bv = *(const bf16x8*)&Vt_lds[df * 16 + l15][sstep * 32 + g * 8];
                o_acc[df] = __builtin_amdgcn_mfma_f32_16x16x32_bf16(ap, bv, o_acc[df], 0, 0, 0);
            }
        }
        __syncthreads();
    }

    short* rb = res + (size_t)b * NT * INNER + (size_t)h * DH;
    float inv[4];
    #pragma unroll
    for (int r = 0; r < 4; ++r) inv[r] = 1.0f / l_run[r];
    #pragma unroll
    for (int df = 0; df < 4; ++df)
        #pragma unroll
        for (int r = 0; r < 4; ++r) {
            int t = q0 + w * 16 + g * 4 + r;
            int d = df * 16 + l15;
            rb[(size_t)t * INNER + d] = (short)f2b(o_acc[df][r] * inv[r]);
        }
}

// ---------------- Kernel C: out projection + bias + residual + transpose ----------------
// computes D[c][t] = sum_i Wout[i][c]*res[t][i]; out[b][c][t] = D + bout[c] + x[b][c][t]
__global__ __launch_bounds__(256) void out_proj(const short* __restrict__ res,
                                                const float* __restrict__ Wout,
                                                const float* __restrict__ bout,
                                                const float* __restrict__ x,
                                                float* __restrict__ out) {
    __shared__ __align__(16) short Wt[128][40];   // [c][i] (transposed)
    __shared__ __align__(16) short Rs[128][40];   // [t][i]

    const int tid  = threadIdx.x;
    const int lane = tid & 63;
    const int w    = tid >> 6;
    const int wr   = w >> 1, wc = w & 1;
    const int l15  = lane & 15, g = lane >> 4;

    const int t0 = blockIdx.x * 128;
    const int c0 = blockIdx.y * 128;
    const int b  = blockIdx.z;

    f32x4 acc[4][4] = {};
    const short* rbase = res + (size_t)b * NT * INNER;

    for (int i0 = 0; i0 < INNER; i0 += 32) {
        // Wt[cc][ii] = Wout[i0+ii][c0+cc] (coalesced float4 along c)
        #pragma unroll
        for (int i = 0; i < 4; ++i) {
            int idx = tid + i * 256;
            int c4 = (idx & 31) * 4, ii = idx >> 5;
            f4 v = *(const f4*)&Wout[(size_t)(i0 + ii) * C + c0 + c4];
            #pragma unroll
            for (int j = 0; j < 4; ++j) Wt[c4 + j][ii] = (short)f2b(v[j]);
        }
        // Rs[tt][ii] = res[t0+tt][i0+ii] (short8 loads)
        #pragma unroll
        for (int i = 0; i < 2; ++i) {
            int idx = tid + i * 256;            // 0..511
            int tt = idx >> 2, ic = idx & 3;
            *(short8*)&Rs[tt][ic * 8] =
                *(const short8*)(rbase + (size_t)(t0 + tt) * INNER + i0 + ic * 8);
        }
        __syncthreads();

        bf16x8 a[4], bb[4];
        #pragma unroll
        for (int m = 0; m < 4; ++m)
            a[m] = *(const bf16x8*)&Wt[wr * 64 + m * 16 + l15][g * 8];
        #pragma unroll
        for (int n = 0; n < 4; ++n)
            bb[n] = *(const bf16x8*)&Rs[wc * 64 + n * 16 + l15][g * 8];
        #pragma unroll
        for (int m = 0; m < 4; ++m)
            #pragma unroll
            for (int n = 0; n < 4; ++n)
                acc[m][n] = __builtin_amdgcn_mfma_f32_16x16x32_bf16(a[m], bb[n], acc[m][n], 0, 0, 0);
        __syncthreads();
    }

    const float* xb = x + (size_t)b * C * NT;
    float* ob = out + (size_t)b * C * NT;
    #pragma unroll
    for (int m = 0; m < 4; ++m) {
        int c = c0 + wr * 64 + m * 16 + g * 4;
        #pragma unroll
        for (int r = 0; r < 4; ++r) {
            float bias = bout[c + r];
            #pragma unroll
            for (int n = 0; n < 4; ++n) {
                int t = t0 + wc * 64 + n * 16 + l15;
                size_t idx = (size_t)(c + r) * NT + t;
                ob[idx] = acc[m][n][r] + bias + xb[idx];
            }
        }
    }
}

extern "C" void kernel_launch(void* const* d_in, const int* in_sizes, int n_in,
                              void* d_out, int out_size, void* d_ws, size_t ws_size,
                              hipStream_t stream) {
    const float* x    = (const float*)d_in[0];
    const float* Wqkv = (const float*)d_in[1];
    const float* bqkv = (const float*)d_in[2];
    const float* Wout = (const float*)d_in[3];
    const float* bout = (const float*)d_in[4];
    float* out = (float*)d_out;

    short* qkv  = (short*)d_ws;                               // 16*1024*1536 bf16 = 50.3 MB
    short* resb = qkv + (size_t)Bn * NT * QKVD;               // 16*1024*512  bf16 = 16.8 MB

    qkv_gemm<<<dim3(QKVD / 128, NT / 128, Bn), 256, 0, stream>>>(x, Wqkv, bqkv, qkv);
    attn<<<dim3(NT / 64, NH, Bn), 256, 0, stream>>>(qkv, resb);
    out_proj<<<dim3(NT / 128, C / 128, Bn), 256, 0, stream>>>(resb, Wout, bout, x, out);
}

// Round 2
// 181.908 us; speedup vs baseline: 1.6761x; 1.6761x over previous
//
#include <hip/hip_runtime.h>
#include <hip/hip_bf16.h>
#include <stdint.h>

typedef short short8 __attribute__((ext_vector_type(8)));
typedef short bf16x8 __attribute__((ext_vector_type(8)));
typedef float f32x4 __attribute__((ext_vector_type(4)));
typedef float f4 __attribute__((ext_vector_type(4)));

constexpr int Bn = 16;     // batch
constexpr int C  = 256;    // channels
constexpr int NT = 1024;   // tokens
constexpr int NH = 8;      // heads
constexpr int INNER = 512;
constexpr int QKVD = 1536;

#define DEVFN __device__ __forceinline__

DEVFN float b2f(unsigned short u) {
    uint32_t x = ((uint32_t)u) << 16; float f; __builtin_memcpy(&f, &x, 4); return f;
}
DEVFN unsigned short f2b_rne(float f) {
    uint32_t x; __builtin_memcpy(&x, &f, 4);
    return (unsigned short)((x + 0x7fffu + ((x >> 16) & 1u)) >> 16);
}
DEVFN unsigned short f2b_rta(float f) {
    uint32_t x; __builtin_memcpy(&x, &f, 4);
    return (unsigned short)((x + 0x8000u) >> 16);
}
DEVFN float exp2_fast(float x) {
    float r; asm("v_exp_f32 %0, %1" : "=v"(r) : "v"(x)); return r;
}

DEVFN void gload16(const void* g, void* l) {
    __builtin_amdgcn_global_load_lds((const __attribute__((address_space(1))) void*)g,
                                     (__attribute__((address_space(3))) void*)l, 16, 0, 0);
}

// ---------- prep_w: Wqkv -> WqkvT bf16 [j'][256] (j' = which*512+h*64+d), Wout -> WoutT bf16 [c][512]
__global__ __launch_bounds__(256) void prep_w(const float* __restrict__ Wqkv,
                                              const float* __restrict__ Wout,
                                              short* __restrict__ WqkvT,
                                              short* __restrict__ WoutT) {
    __shared__ float T[64][65];
    const int tid = threadIdx.x;
    if (blockIdx.z == 0) {
        if (blockIdx.y >= 4) return;
        int jb = blockIdx.x, cb = blockIdx.y;
        int jpb = jb * 64;
        int jorig0 = ((jpb >> 6) & 7) * 192 + (jpb >> 9) * 64;
        #pragma unroll
        for (int it = 0; it < 4; ++it) {
            int cc = (tid >> 4) + it * 16, d4 = (tid & 15) * 4;
            f4 v = *(const f4*)&Wqkv[(size_t)(cb * 64 + cc) * QKVD + jorig0 + d4];
            T[cc][d4] = v[0]; T[cc][d4 + 1] = v[1]; T[cc][d4 + 2] = v[2]; T[cc][d4 + 3] = v[3];
        }
        __syncthreads();
        int d = tid >> 2, cs = tid & 3;
        short8 o0, o1;
        #pragma unroll
        for (int k = 0; k < 8; ++k) o0[k] = (short)f2b_rne(T[cs * 16 + k][d]);
        #pragma unroll
        for (int k = 0; k < 8; ++k) o1[k] = (short)f2b_rne(T[cs * 16 + 8 + k][d]);
        short* orow = WqkvT + (size_t)(jpb + d) * C + cb * 64 + cs * 16;
        *(short8*)orow = o0; *(short8*)(orow + 8) = o1;
    } else {
        if (blockIdx.x >= 4) return;
        int cb = blockIdx.x, ib = blockIdx.y;
        #pragma unroll
        for (int it = 0; it < 4; ++it) {
            int ii = (tid >> 4) + it * 16, c4 = (tid & 15) * 4;
            f4 v = *(const f4*)&Wout[(size_t)(ib * 64 + ii) * C + cb * 64 + c4];
            T[ii][c4] = v[0]; T[ii][c4 + 1] = v[1]; T[ii][c4 + 2] = v[2]; T[ii][c4 + 3] = v[3];
        }
        __syncthreads();
        int cL = tid >> 2, is = tid & 3;
        short8 o0, o1;
        #pragma unroll
        for (int k = 0; k < 8; ++k) o0[k] = (short)f2b_rne(T[is * 16 + k][cL]);
        #pragma unroll
        for (int k = 0; k < 8; ++k) o1[k] = (short)f2b_rne(T[is * 16 + 8 + k][cL]);
        short* orow = WoutT + (size_t)(cb * 64 + cL) * INNER + ib * 64 + is * 16;
        *(short8*)orow = o0; *(short8*)(orow + 8) = o1;
    }
}

// ---------- transpose_x: x fp32 [b][c][t] -> xT bf16 [b][t][c]
__global__ __launch_bounds__(256) void transpose_x(const float* __restrict__ x,
                                                   short* __restrict__ xT) {
    __shared__ float T[64][65];
    const int tid = threadIdx.x;
    const int tb = blockIdx.x, cb = blockIdx.y, b = blockIdx.z;
    const float* xb = x + (size_t)b * C * NT;
    #pragma unroll
    for (int it = 0; it < 4; ++it) {
        int cc = (tid >> 4) + it * 16, t4 = (tid & 15) * 4;
        f4 v = *(const f4*)&xb[(size_t)(cb * 64 + cc) * NT + tb * 64 + t4];
        T[cc][t4] = v[0]; T[cc][t4 + 1] = v[1]; T[cc][t4 + 2] = v[2]; T[cc][t4 + 3] = v[3];
    }
    __syncthreads();
    int tL = tid >> 2, cs = tid & 3;
    short8 o0, o1;
    #pragma unroll
    for (int k = 0; k < 8; ++k) o0[k] = (short)f2b_rne(T[cs * 16 + k][tL]);
    #pragma unroll
    for (int k = 0; k < 8; ++k) o1[k] = (short)f2b_rne(T[cs * 16 + 8 + k][tL]);
    short* orow = xT + ((size_t)b * NT + tb * 64 + tL) * C + cb * 64 + cs * 16;
    *(short8*)orow = o0; *(short8*)(orow + 8) = o1;
}

// ---------- qkv_gemm: C[t][j'] = xT . WqkvT^T, +bias(perm), Q-part scaled by SCALE*log2e
__global__ __launch_bounds__(256) void qkv_gemm(const short* __restrict__ xT,
                                                const short* __restrict__ WqkvT,
                                                const float* __restrict__ bqkv,
                                                short* __restrict__ qkv) {
    __shared__ __align__(16) short As[128][64];
    __shared__ __align__(16) short Bs[128][64];
    const int tid = threadIdx.x, l = tid & 63, w = tid >> 6;
    const int l15 = l & 15, g = l >> 4;
    const int wr = w >> 1, wc = w & 1;
    const int lr = l >> 3, ls = l & 7;
    const int j0 = blockIdx.x * 128, t0 = blockIdx.y * 128, b = blockIdx.z;
    f32x4 acc[4][4] = {};
    const short* Ab = xT + ((size_t)b * NT + t0) * C;
    const short* Bb = WqkvT + (size_t)j0 * C;

    for (int k0 = 0; k0 < C; k0 += 64) {
        __syncthreads();
        #pragma unroll
        for (int i = 0; i < 4; ++i) {
            int r0 = w * 32 + i * 8;
            int row = r0 + lr;
            int slot = ls ^ (row & 7);
            gload16(Ab + (size_t)row * C + k0 + slot * 8, &As[r0][0]);
            gload16(Bb + (size_t)row * C + k0 + slot * 8, &Bs[r0][0]);
        }
        __syncthreads();
        bf16x8 a[4][2], bb[4][2];
        #pragma unroll
        for (int m = 0; m < 4; ++m) {
            int row = wr * 64 + m * 16 + l15;
            const char* base = (const char*)&As[row][0];
            #pragma unroll
            for (int kk = 0; kk < 2; ++kk)
                a[m][kk] = *(const bf16x8*)(base + (((kk * 4 + g) ^ (row & 7)) << 4));
        }
        #pragma unroll
        for (int n = 0; n < 4; ++n) {
            int row = wc * 64 + n * 16 + l15;
            const char* base = (const char*)&Bs[row][0];
            #pragma unroll
            for (int kk = 0; kk < 2; ++kk)
                bb[n][kk] = *(const bf16x8*)(base + (((kk * 4 + g) ^ (row & 7)) << 4));
        }
        #pragma unroll
        for (int m = 0; m < 4; ++m)
            #pragma unroll
            for (int n = 0; n < 4; ++n) {
                acc[m][n] = __builtin_amdgcn_mfma_f32_16x16x32_bf16(a[m][0], bb[n][0], acc[m][n], 0, 0, 0);
                acc[m][n] = __builtin_amdgcn_mfma_f32_16x16x32_bf16(a[m][1], bb[n][1], acc[m][n], 0, 0, 0);
            }
    }

    short* qb = qkv + ((size_t)b * NT + t0) * QKVD;
    #pragma unroll
    for (int n = 0; n < 4; ++n) {
        int j = j0 + wc * 64 + n * 16 + l15;
        int jorig = ((j >> 6) & 7) * 192 + (j >> 9) * 64 + (j & 63);
        float bias = bqkv[jorig];
        float scale = (j < 512) ? 0.18033688f : 1.0f;   // SCALE * log2(e) folded into Q
        #pragma unroll
        for (int m = 0; m < 4; ++m) {
            #pragma unroll
            for (int r = 0; r < 4; ++r) {
                int t = wr * 64 + m * 16 + g * 4 + r;
                qb[(size_t)t * QKVD + j] = (short)f2b_rne((acc[m][n][r] + bias) * scale);
            }
        }
    }
}

// ---------- transpose_v: qkv V-part [b][t][1024+hd] -> Vt [b][hd][t]
__global__ __launch_bounds__(256) void transpose_v(const short* __restrict__ qkv,
                                                   short* __restrict__ Vt) {
    __shared__ __align__(16) short T[64][68];
    const int tid = threadIdx.x;
    const int tb = blockIdx.x, vb = blockIdx.y, b = blockIdx.z;
    {
        int tt = tid >> 2, seg = tid & 3;
        const short* src = qkv + ((size_t)b * NT + tb * 64 + tt) * QKVD + 1024 + vb * 64 + seg * 16;
        *(short8*)&T[tt][seg * 16] = *(const short8*)src;
        *(short8*)&T[tt][seg * 16 + 8] = *(const short8*)(src + 8);
    }
    __syncthreads();
    int hd = tid & 63, ts = tid >> 6;
    short8 o0, o1;
    #pragma unroll
    for (int k = 0; k < 8; ++k) o0[k] = T[ts * 16 + k][hd];
    #pragma unroll
    for (int k = 0; k < 8; ++k) o1[k] = T[ts * 16 + 8 + k][hd];
    short* orow = Vt + ((size_t)b * INNER + vb * 64 + hd) * NT + tb * 64 + ts * 16;
    *(short8*)orow = o0; *(short8*)(orow + 8) = o1;
}

// ---------- attn: flash attention, 128 q-rows/block, 4 waves x 32 q-rows, exp2 domain
__global__ __launch_bounds__(256) void attn(const short* __restrict__ qkv,
                                            const short* __restrict__ Vt,
                                            short* __restrict__ res) {
    __shared__ __align__(16) short QP[128][64];   // Q then P (wave-private rows)
    __shared__ __align__(16) short Kl[64][64];
    __shared__ __align__(16) short Vl[64][64];    // [d][key]
    const int tid = threadIdx.x, l = tid & 63, w = tid >> 6;
    const int l15 = l & 15, g = l >> 4;
    const int lr = l >> 3, ls = l & 7;
    const int q0 = blockIdx.x * 128, h = blockIdx.y, b = blockIdx.z;

    const short* Qg = qkv + (size_t)b * NT * QKVD + h * 64;
    const short* Kg = Qg + 512;
    const short* Vg = Vt + ((size_t)b * INNER + h * 64) * NT;

    // stage Q (swizzled source -> linear LDS)
    #pragma unroll
    for (int i = 0; i < 4; ++i) {
        int r0 = w * 32 + i * 8;
        int row = r0 + lr;
        gload16(Qg + (size_t)(q0 + row) * QKVD + (ls ^ (row & 7)) * 8, &QP[r0][0]);
    }
    __syncthreads();
    bf16x8 aq[2][2];
    #pragma unroll
    for (int qg = 0; qg < 2; ++qg) {
        int row = w * 32 + qg * 16 + l15;
        const char* base = (const char*)&QP[row][0];
        aq[qg][0] = *(const bf16x8*)(base + (((g) ^ (row & 7)) << 4));
        aq[qg][1] = *(const bf16x8*)(base + (((4 + g) ^ (row & 7)) << 4));
    }

    float m_run[2][4], l_run[2][4];
    f32x4 o[2][4] = {};
    #pragma unroll
    for (int qg = 0; qg < 2; ++qg)
        #pragma unroll
        for (int r = 0; r < 4; ++r) { m_run[qg][r] = -1e30f; l_run[qg][r] = 0.f; }

    char* qpb = (char*)&QP[0][0];

    for (int kt = 0; kt < NT / 64; ++kt) {
        __syncthreads();
        #pragma unroll
        for (int i = 0; i < 2; ++i) {
            int r0 = w * 16 + i * 8;
            int row = r0 + lr;
            gload16(Kg + (size_t)(kt * 64 + row) * QKVD + (ls ^ (row & 7)) * 8, &Kl[r0][0]);
            gload16(Vg + (size_t)row * NT + kt * 64 + (ls ^ (row & 7)) * 8, &Vl[r0][0]);
        }
        __syncthreads();

        // S = Q.K^T  (log2 domain: scale folded into Q)
        f32x4 s[2][4];
        #pragma unroll
        for (int n = 0; n < 4; ++n) {
            int row = n * 16 + l15;
            const char* base = (const char*)&Kl[row][0];
            bf16x8 bk0 = *(const bf16x8*)(base + (((g) ^ (row & 7)) << 4));
            bf16x8 bk1 = *(const bf16x8*)(base + (((4 + g) ^ (row & 7)) << 4));
            #pragma unroll
            for (int qg = 0; qg < 2; ++qg) {
                f32x4 z = {};
                z = __builtin_amdgcn_mfma_f32_16x16x32_bf16(aq[qg][0], bk0, z, 0, 0, 0);
                s[qg][n] = __builtin_amdgcn_mfma_f32_16x16x32_bf16(aq[qg][1], bk1, s[qg][n] = z, 0, 0, 0);
            }
        }

        // online softmax per 32-row group, P -> LDS (wave-private rows, swizzled)
        #pragma unroll
        for (int qg = 0; qg < 2; ++qg) {
            float mt[4];
            #pragma unroll
            for (int r = 0; r < 4; ++r) {
                float v = fmaxf(fmaxf(s[0 + qg][0][r], s[qg][1][r]), fmaxf(s[qg][2][r], s[qg][3][r]));
                #pragma unroll
                for (int msk = 1; msk < 16; msk <<= 1) v = fmaxf(v, __shfl_xor(v, msk, 64));
                mt[r] = v;
            }
            float al[4];
            #pragma unroll
            for (int r = 0; r < 4; ++r) {
                float mn = fmaxf(m_run[qg][r], mt[r]);
                al[r] = exp2_fast(m_run[qg][r] - mn);
                m_run[qg][r] = mn;
            }
            float rs[4] = {0.f, 0.f, 0.f, 0.f};
            int rowb = w * 32 + qg * 16 + g * 4;
            int colb = (l15 & 7) * 2;
            #pragma unroll
            for (int n = 0; n < 4; ++n) {
                int cslot = n * 2 + (l15 >> 3);
                #pragma unroll
                for (int r = 0; r < 4; ++r) {
                    float p = exp2_fast(s[qg][n][r] - m_run[qg][r]);
                    rs[r] += p;
                    int row = rowb + r;
                    *(unsigned short*)(qpb + row * 128 + ((cslot ^ (row & 7)) << 4) + colb) = f2b_rta(p);
                }
            }
            #pragma unroll
            for (int r = 0; r < 4; ++r) {
                float v = rs[r];
                #pragma unroll
                for (int msk = 1; msk < 16; msk <<= 1) v += __shfl_xor(v, msk, 64);
                l_run[qg][r] = l_run[qg][r] * al[r] + v;
            }
            #pragma unroll
            for (int df = 0; df < 4; ++df)
                #pragma unroll
                for (int r = 0; r < 4; ++r) o[qg][df][r] *= al[r];
        }

        // V^T fragments
        bf16x8 bv[4][2];
        #pragma unroll
        for (int df = 0; df < 4; ++df) {
            int row = df * 16 + l15;
            const char* base = (const char*)&Vl[row][0];
            bv[df][0] = *(const bf16x8*)(base + (((g) ^ (row & 7)) << 4));
            bv[df][1] = *(const bf16x8*)(base + (((4 + g) ^ (row & 7)) << 4));
        }

        asm volatile("s_waitcnt lgkmcnt(0)" ::: "memory");
        __builtin_amdgcn_sched_barrier(0);

        // O += P.V
        #pragma unroll
        for (int qg = 0; qg < 2; ++qg) {
            int row = w * 32 + qg * 16 + l15;
            const char* base = qpb + row * 128;
            bf16x8 ap0 = *(const bf16x8*)(base + (((g) ^ (row & 7)) << 4));
            bf16x8 ap1 = *(const bf16x8*)(base + (((4 + g) ^ (row & 7)) << 4));
            #pragma unroll
            for (int df = 0; df < 4; ++df) {
                o[qg][df] = __builtin_amdgcn_mfma_f32_16x16x32_bf16(ap0, bv[df][0], o[qg][df], 0, 0, 0);
                o[qg][df] = __builtin_amdgcn_mfma_f32_16x16x32_bf16(ap1, bv[df][1], o[qg][df], 0, 0, 0);
            }
        }
    }

    short* rb = res + (size_t)b * NT * INNER + h * 64;
    #pragma unroll
    for (int qg = 0; qg < 2; ++qg) {
        float inv[4];
        #pragma unroll
        for (int r = 0; r < 4; ++r) inv[r] = 1.0f / l_run[qg][r];
        #pragma unroll
        for (int df = 0; df < 4; ++df)
            #pragma unroll
            for (int r = 0; r < 4; ++r) {
                int t = q0 + w * 32 + qg * 16 + g * 4 + r;
                rb[(size_t)t * INNER + df * 16 + l15] = (short)f2b_rne(o[qg][df][r] * inv[r]);
            }
    }
}

// ---------- out_proj: out[b][c][t] = (Wout^T.res^T)[c][t] + bout[c] + x[b][c][t]
__global__ __launch_bounds__(256) void out_proj(const short* __restrict__ WoutT,
                                                const short* __restrict__ res,
                                                const float* __restrict__ bout,
                                                const float* __restrict__ x,
                                                float* __restrict__ out) {
    __shared__ __align__(16) short As[128][64];   // WoutT rows (c)
    __shared__ __align__(16) short Bs[128][64];   // res rows (t)
    const int tid = threadIdx.x, l = tid & 63, w = tid >> 6;
    const int l15 = l & 15, g = l >> 4;
    const int wr = w >> 1, wc = w & 1;
    const int lr = l >> 3, ls = l & 7;
    const int t0 = blockIdx.x * 128, c0 = blockIdx.y * 128, b = blockIdx.z;
    f32x4 acc[4][4] = {};
    const short* Ab = WoutT + (size_t)c0 * INNER;
    const short* Bb = res + ((size_t)b * NT + t0) * INNER;

    for (int k0 = 0; k0 < INNER; k0 += 64) {
        __syncthreads();
        #pragma unroll
        for (int i = 0; i < 4; ++i) {
            int r0 = w * 32 + i * 8;
            int row = r0 + lr;
            int slot = ls ^ (row & 7);
            gload16(Ab + (size_t)row * INNER + k0 + slot * 8, &As[r0][0]);
            gload16(Bb + (size_t)row * INNER + k0 + slot * 8, &Bs[r0][0]);
        }
        __syncthreads();
        bf16x8 a[4][2], bb[4][2];
        #pragma unroll
        for (int m = 0; m < 4; ++m) {
            int row = wr * 64 + m * 16 + l15;
            const char* base = (const char*)&As[row][0];
            #pragma unroll
            for (int kk = 0; kk < 2; ++kk)
                a[m][kk] = *(const bf16x8*)(base + (((kk * 4 + g) ^ (row & 7)) << 4));
        }
        #pragma unroll
        for (int n = 0; n < 4; ++n) {
            int row = wc * 64 + n * 16 + l15;
            const char* base = (const char*)&Bs[row][0];
            #pragma unroll
            for (int kk = 0; kk < 2; ++kk)
                bb[n][kk] = *(const bf16x8*)(base + (((kk * 4 + g) ^ (row & 7)) << 4));
        }
        #pragma unroll
        for (int m = 0; m < 4; ++m)
            #pragma unroll
            for (int n = 0; n < 4; ++n) {
                acc[m][n] = __builtin_amdgcn_mfma_f32_16x16x32_bf16(a[m][0], bb[n][0], acc[m][n], 0, 0, 0);
                acc[m][n] = __builtin_amdgcn_mfma_f32_16x16x32_bf16(a[m][1], bb[n][1], acc[m][n], 0, 0, 0);
            }
    }

    const float* xb = x + (size_t)b * C * NT;
    float* ob = out + (size_t)b * C * NT;
    #pragma unroll
    for (int m = 0; m < 4; ++m) {
        #pragma unroll
        for (int r = 0; r < 4; ++r) {
            int c = c0 + wr * 64 + m * 16 + g * 4 + r;
            float bias = bout[c];
            #pragma unroll
            for (int n = 0; n < 4; ++n) {
                int t = t0 + wc * 64 + n * 16 + l15;
                size_t idx = (size_t)c * NT + t;
                ob[idx] = acc[m][n][r] + bias + xb[idx];
            }
        }
    }
}

extern "C" void kernel_launch(void* const* d_in, const int* in_sizes, int n_in,
                              void* d_out, int out_size, void* d_ws, size_t ws_size,
                              hipStream_t stream) {
    const float* x    = (const float*)d_in[0];
    const float* Wqkv = (const float*)d_in[1];
    const float* bqkv = (const float*)d_in[2];
    const float* Wout = (const float*)d_in[3];
    const float* bout = (const float*)d_in[4];
    float* out = (float*)d_out;

    char* ws = (char*)d_ws;
    short* qkvb  = (short*)(ws);                       // 50,331,648 B
    short* VtB   = (short*)(ws + 50331648);            // 16,777,216 B
    short* xTres = (short*)(ws + 67108864);            // 16,777,216 B (xT then res)
    short* WqT   = (short*)(ws + 83886080);            //    786,432 B
    short* WoT   = (short*)(ws + 84672512);            //    262,144 B

    prep_w<<<dim3(24, 8, 2), 256, 0, stream>>>(Wqkv, Wout, WqT, WoT);
    transpose_x<<<dim3(16, 4, 16), 256, 0, stream>>>(x, xTres);
    qkv_gemm<<<dim3(12, 8, 16), 256, 0, stream>>>(xTres, WqT, bqkv, qkvb);
    transpose_v<<<dim3(16, 8, 16), 256, 0, stream>>>(qkvb, VtB);
    attn<<<dim3(8, 8, 16), 256, 0, stream>>>(qkvb, VtB, xTres);
    out_proj<<<dim3(8, 2, 16), 256, 0, stream>>>(WoT, xTres, bout, x, out);
}